// Round 10
// baseline (311.196 us; speedup 1.0000x reference)
//
#include <hip/hip_runtime.h>
#include <hip/hip_bf16.h>

typedef __attribute__((ext_vector_type(8))) short bf16x8;
typedef __attribute__((ext_vector_type(4))) float f32x4;
typedef __attribute__((ext_vector_type(4))) unsigned int u32x4;

#define HW (512 * 512)
#define TW 64
#define SLOTS 6                  // 4 read + 2 write slots, disjoint
#define PXG (SLOTS * 66)         // 396 pixels per ic-group
#define TILE_B (4 * PXG * 16)    // 25344
#define DUMMY TILE_B             // 1 KB dummy scratch at 25344

#define SCHED() __builtin_amdgcn_sched_barrier(0)

__device__ __forceinline__ unsigned short f2bf(float f) {
    unsigned u = __builtin_bit_cast(unsigned, f);
    u += 0x7FFFu + ((u >> 16) & 1u);   // RNE
    return (unsigned short)(u >> 16);
}

// batch = rows {row0, row0+1}: 768 units = (g:4)x(hh:2)x(ww:96), real ww<66.
// Uniform 24 load-instrs per wave -> exact per-wave vmcnt.
__device__ __forceinline__ void issueB(const float* __restrict__ xb, int row0, int w0,
                                       float (&sv)[3][8]) {
    #pragma unroll
    for (int k = 0; k < 3; ++k) {
        int u = (int)threadIdx.x + k * 256;
        int g = u / 192, r = u - g * 192, hh = r / 96, ww = r - hh * 96;
        int wwc = ww < 66 ? ww : 65;
        int row = row0 + hh;
        int cl  = w0 + wwc - 1;
        bool ok = (ww < 66) & (row < 512) & ((unsigned)cl < 512u);
        int rowc = row < 512 ? row : 511;
        int clc  = cl < 0 ? 0 : (cl > 511 ? 511 : cl);
        const float* src = xb + (size_t)(g * 8) * HW + rowc * 512 + clc;
        #pragma unroll
        for (int j = 0; j < 8; ++j) { float v = src[(size_t)j * HW]; sv[k][j] = ok ? v : 0.f; }
    }
}

__device__ __forceinline__ void writeB(char* smem, int wsb, float (&sv)[3][8]) {
    #pragma unroll
    for (int k = 0; k < 3; ++k) {
        int u = (int)threadIdx.x + k * 256;
        int g = u / 192, r = u - g * 192, hh = r / 96, ww = r - hh * 96;
        int slot = wsb + hh; if (slot >= SLOTS) slot -= SLOTS;
        int byte = (ww < 66) ? (g * PXG + slot * 66 + ww) * 16
                             : (DUMMY + ((int)threadIdx.x & 63) * 16);
        unsigned q0 = (unsigned)f2bf(sv[k][0]) | ((unsigned)f2bf(sv[k][1]) << 16);
        unsigned q1 = (unsigned)f2bf(sv[k][2]) | ((unsigned)f2bf(sv[k][3]) << 16);
        unsigned q2 = (unsigned)f2bf(sv[k][4]) | ((unsigned)f2bf(sv[k][5]) << 16);
        unsigned q3 = (unsigned)f2bf(sv[k][6]) | ((unsigned)f2bf(sv[k][7]) << 16);
        u32x4 q = { q0, q1, q2, q3 };
        *(u32x4*)(smem + byte) = q;
    }
}

// W: vmcnt immediate (-1 = none). Order: wait -> writeB(cur) -> issueB(nxt) -> MFMA -> stores -> bar.
template<int W, bool WR, bool ISS, bool BAR>
__device__ __forceinline__ void body(char* smem, const float* __restrict__ xb,
                                     float* __restrict__ ob, bf16x8 (&wf)[9][2],
                                     float (&cur)[3][8], float (&nxt)[3][8],
                                     int srb, int rowbase, int w0,
                                     int wv, int col16, int g4) {
    if constexpr (W == 24) { asm volatile("s_waitcnt vmcnt(24)" ::: "memory"); SCHED(); }
    else if constexpr (W == 28) { asm volatile("s_waitcnt vmcnt(28)" ::: "memory"); SCHED(); }
    else if constexpr (W == 32) { asm volatile("s_waitcnt vmcnt(32)" ::: "memory"); SCHED(); }
    else if constexpr (W == 8)  { asm volatile("s_waitcnt vmcnt(8)"  ::: "memory"); SCHED(); }

    if (WR) {   // batch(t) -> write slots (disjoint from read slots)
        int wsb = srb + 4; if (wsb >= SLOTS) wsb -= SLOTS;
        writeB(smem, wsb, cur);
    }
    if (ISS) issueB(xb, rowbase + 7, w0, nxt);   // batch(t+2) = rows 2t+7, 2t+8

    f32x4 acc[2][2];
    {
        f32x4 z = {0.f, 0.f, 0.f, 0.f};
        acc[0][0] = z; acc[0][1] = z; acc[1][0] = z; acc[1][1] = z;
    }
    int rs[3];
    #pragma unroll
    for (int dh = 0; dh < 3; ++dh) {
        int s = srb + (wv & 1) + dh; if (s >= SLOTS) s -= SLOTS;
        rs[dh] = s * 66;
    }
    const int wcb = (wv >> 1) * 32;
    const char* xg = smem + g4 * (PXG * 16);
    #pragma unroll
    for (int dh = 0; dh < 3; ++dh) {
        #pragma unroll
        for (int dw = 0; dw < 3; ++dw) {
            const int tap = dh * 3 + dw;
            #pragma unroll
            for (int m = 0; m < 2; ++m) {
                bf16x8 a = *(const bf16x8*)(xg + (rs[dh] + wcb + m * 16 + col16 + dw) * 16);
                acc[m][0] = __builtin_amdgcn_mfma_f32_16x16x32_bf16(a, wf[tap][0], acc[m][0], 0, 0, 0);
                acc[m][1] = __builtin_amdgcn_mfma_f32_16x16x32_bf16(a, wf[tap][1], acc[m][1], 0, 0, 0);
            }
        }
    }
    {
        float* orow = ob + (size_t)(rowbase + (wv & 1)) * 512 + w0 + wcb;
        #pragma unroll
        for (int m = 0; m < 2; ++m)
            #pragma unroll
            for (int n = 0; n < 2; ++n)
                *(f32x4*)(orow + (size_t)(n * 16 + col16) * HW + m * 16 + g4 * 4) = acc[m][n];
    }
    if (BAR) {
        asm volatile("s_waitcnt lgkmcnt(0)" ::: "memory");
        SCHED();
        __builtin_amdgcn_s_barrier();
        SCHED();
    }
}

__global__ __launch_bounds__(256, 2)
void conv3x3_mfma(const float* __restrict__ x,
                  const float* __restrict__ wk,
                  float* __restrict__ out) {
    __shared__ __align__(16) char smem[TILE_B + 1024];   // 26368 B

    const int tid   = (int)threadIdx.x;
    const int lane  = tid & 63;
    const int wv    = tid >> 6;        // 0..3
    const int col16 = lane & 15;
    const int g4    = lane >> 4;

    const int w0    = blockIdx.x * TW;
    const int hbase = blockIdx.y * 64;
    const int b     = blockIdx.z;

    const float* xb = x + (size_t)b * 32 * HW;
    float* ob = out + (size_t)b * 32 * HW;

    // ---- prologue A: x rows hbase-1..hbase+2 (slots 0..3), 1056 units -> regs ----
    float svp[5][8];
    #pragma unroll
    for (int k = 0; k < 5; ++k) {
        if (k == 4 && tid >= 32) continue;
        int u = (k < 4) ? tid + k * 256 : 1024 + tid;
        int g = u / 264, p = u - g * 264;
        int row = hbase + p / 66 - 1, cl = w0 + p % 66 - 1;
        bool ok = ((unsigned)row < 512u) & ((unsigned)cl < 512u);
        int rowc = row < 0 ? 0 : (row > 511 ? 511 : row);
        int clc  = cl  < 0 ? 0 : (cl  > 511 ? 511 : cl);
        const float* src = xb + (size_t)(g * 8) * HW + rowc * 512 + clc;
        #pragma unroll
        for (int j = 0; j < 8; ++j) { float v = src[(size_t)j * HW]; svp[k][j] = ok ? v : 0.f; }
    }

    // ---- prologue B: weights -> registers directly (one-time; L2-cached) ----
    bf16x8 wf[9][2];
    #pragma unroll
    for (int tap = 0; tap < 9; ++tap) {
        #pragma unroll
        for (int n = 0; n < 2; ++n) {
            bf16x8 f;
            #pragma unroll
            for (int j = 0; j < 8; ++j)
                f[j] = (short)f2bf(wk[(n * 16 + col16) * 288 + (g4 * 8 + j) * 9 + tap]);
            wf[tap][n] = f;
        }
    }

    // ---- prologue C: write x slots 0..3 to LDS ----
    #pragma unroll
    for (int k = 0; k < 5; ++k) {
        if (k == 4 && tid >= 32) continue;
        int u = (k < 4) ? tid + k * 256 : 1024 + tid;
        int g = u / 264, p = u - g * 264;   // p = slot*66+ww directly
        unsigned q0 = (unsigned)f2bf(svp[k][0]) | ((unsigned)f2bf(svp[k][1]) << 16);
        unsigned q1 = (unsigned)f2bf(svp[k][2]) | ((unsigned)f2bf(svp[k][3]) << 16);
        unsigned q2 = (unsigned)f2bf(svp[k][4]) | ((unsigned)f2bf(svp[k][5]) << 16);
        unsigned q3 = (unsigned)f2bf(svp[k][6]) | ((unsigned)f2bf(svp[k][7]) << 16);
        u32x4 q = { q0, q1, q2, q3 };
        *(u32x4*)(smem + (g * PXG + p) * 16) = q;
    }

    // ---- prologue D: issue batch0 (rows 3,4) and batch1 (rows 5,6); keep in flight ----
    float svA[3][8], svB[3][8], svC[3][8];
    SCHED();
    issueB(xb, hbase + 3, w0, svA);
    issueB(xb, hbase + 5, w0, svB);
    SCHED();
    asm volatile("s_waitcnt lgkmcnt(0)" ::: "memory");
    SCHED();
    __builtin_amdgcn_s_barrier();    // raw: batches 0,1 stay in flight
    SCHED();

    // batch b lives in sv[b%3]; iter t: cur = sv[t%3], issues batch(t+2) -> sv[(t+2)%3]
    // t=0
    body<24, 1, 1, 1>(smem, xb, ob, wf, svA, svC, 0, hbase,     w0, wv, col16, g4);
    // t=1
    body<28, 1, 1, 1>(smem, xb, ob, wf, svB, svA, 2, hbase + 2, w0, wv, col16, g4);
    // t=2..28: 9 static trios, steady vmcnt(32)
    int srb = 4;
    #pragma unroll 1
    for (int tq = 0; tq < 9; ++tq) {
        int t0 = 2 + 3 * tq;
        body<32, 1, 1, 1>(smem, xb, ob, wf, svC, svB, srb, hbase + 2 * t0,       w0, wv, col16, g4);
        srb += 2; if (srb >= SLOTS) srb -= SLOTS;
        body<32, 1, 1, 1>(smem, xb, ob, wf, svA, svC, srb, hbase + 2 * (t0 + 1), w0, wv, col16, g4);
        srb += 2; if (srb >= SLOTS) srb -= SLOTS;
        body<32, 1, 1, 1>(smem, xb, ob, wf, svB, svA, srb, hbase + 2 * (t0 + 2), w0, wv, col16, g4);
        srb += 2; if (srb >= SLOTS) srb -= SLOTS;
    }
    // t=29: write batch29 (svC); no issue
    body<32, 1, 0, 1>(smem, xb, ob, wf, svC, svB, srb, hbase + 58, w0, wv, col16, g4);
    srb += 2; if (srb >= SLOTS) srb -= SLOTS;   // -> 0
    // t=30: write batch30 (svA); no issue
    body<8, 1, 0, 1>(smem, xb, ob, wf, svA, svB, srb, hbase + 60, w0, wv, col16, g4);
    srb += 2; if (srb >= SLOTS) srb -= SLOTS;   // -> 2
    // t=31: compute only
    body<-1, 0, 0, 0>(smem, xb, ob, wf, svB, svC, srb, hbase + 62, w0, wv, col16, g4);
}

extern "C" void kernel_launch(void* const* d_in, const int* in_sizes, int n_in,
                              void* d_out, int out_size, void* d_ws, size_t ws_size,
                              hipStream_t stream) {
    const float* x  = (const float*)d_in[0];
    const float* wk = (const float*)d_in[1];
    float* out = (float*)d_out;
    dim3 grid(512 / TW, 512 / 64, 16);   // (8, 8, 16) = 1024 blocks
    conv3x3_mfma<<<grid, 256, 0, stream>>>(x, wk, out);
}

// Round 11
// 271.211 us; speedup vs baseline: 1.1474x; 1.1474x over previous
//
#include <hip/hip_runtime.h>
#include <hip/hip_bf16.h>

typedef __attribute__((ext_vector_type(8))) short bf16x8;
typedef __attribute__((ext_vector_type(4))) float f32x4;
typedef __attribute__((ext_vector_type(4))) unsigned int u32x4;

#define HW (512 * 512)
#define TW 64
#define SLOTS 6                  // tile row slots: 4 read + 2 write, disjoint
#define PXG (SLOTS * 66)         // 396 pixels per ic-group
#define TILE_B (4 * PXG * 16)    // 25344: bf16 [g][pixel] MFMA tile
#define STAGE_HALF 19456         // f32 stage: 32ch x 2row x 288B = 18432 real + 1KB pad
#define SREAL 18432
#define DUMMY (TILE_B + 2 * STAGE_HALF)   // 64256; dummy scratch 1KB -> total 65280 <= 64KB granule

#define SCHED() __builtin_amdgcn_sched_barrier(0)

__device__ __forceinline__ unsigned short f2bf(float f) {
    unsigned u = __builtin_bit_cast(unsigned, f);
    u += 0x7FFFu + ((u >> 16) & 1u);   // RNE
    return (unsigned short)(u >> 16);
}

__device__ __forceinline__ void gll16(const float* g, char* l) {
    __builtin_amdgcn_global_load_lds(
        (const __attribute__((address_space(1))) void*)g,
        (__attribute__((address_space(3))) void*)l, 16, 0, 0);
}

// stage rows {row0,row0+1} of all 32 ch into stage half: layout [ch:32][hh:2][72 f32].
// 19 x 1KB gll instrs: waves 0-2 issue 5, wave 3 issues 4 (vmcnt(4) drains all).
__device__ __forceinline__ void issue_stage(const float* __restrict__ xb, int row0,
                                            int w0, char* smem, int half, int wvu) {
    const int lane = (int)threadIdx.x & 63;
    char* base = smem + TILE_B + half * STAGE_HALF;
    #pragma unroll
    for (int i = 0; i < 5; ++i) {
        if (wvu == 3 && i == 4) continue;          // wave-uniform
        int ob = (wvu * 5 + i) * 1024;
        int o  = ob + lane * 16;
        int o2 = o < (SREAL - 1) ? o : (SREAL - 1);   // pad lanes -> harmless clamp
        int ch = o2 / 576;
        int rem = o2 - ch * 576;
        int hh = rem / 288;
        int wl = (rem - hh * 288) >> 2;               // 0..71 (mult of 4 for real lanes)
        int row = row0 + hh; row = row < 511 ? row : 511;
        int cb = w0 - 4 + wl;
        cb = cb < 0 ? 0 : (cb > 508 ? 508 : cb);      // stays 16B-aligned
        gll16(xb + (size_t)ch * HW + row * 512 + cb, base + ob);
    }
}

template<bool TRANS, bool GLL, bool BAR>
__device__ __forceinline__ void body(char* smem, const float* __restrict__ xb,
                                     float* __restrict__ ob, bf16x8 (&wf)[9][2],
                                     int srb, int half, int rowbase, int w0,
                                     int wv, int wvu, int col16, int g4) {
    // ---- issue loads for t+1 (other stage half; lands during this body) ----
    if (GLL) issue_stage(xb, rowbase + 5, w0, smem, half ^ 1, wvu);

    // ---- transpose+convert stage[half] (x rows rowbase+3,+4) -> tile slots srb+4,srb+5 ----
    if (TRANS) {
        const char* sb = smem + TILE_B + half * STAGE_HALF;
        const int rowA = rowbase + 3;
        #pragma unroll
        for (int k = 0; k < 3; ++k) {
            if (k == 2 && threadIdx.x >= 32) continue;
            int u = (k < 2) ? (int)threadIdx.x + k * 256 : 512 + (int)threadIdx.x;
            int g = u / 136, r = u - g * 136, sl = r / 68, ww = r - sl * 68;
            float v[8];
            int ba = g * 8 * 576 + sl * 288 + (ww + 3) * 4;
            #pragma unroll
            for (int j = 0; j < 8; ++j) v[j] = *(const float*)(sb + ba + j * 576);
            bool ok = (ww < 66) & ((unsigned)(w0 + ww - 1) < 512u) & (rowA + sl < 512);
            #pragma unroll
            for (int j = 0; j < 8; ++j) v[j] = ok ? v[j] : 0.f;
            unsigned q0 = (unsigned)f2bf(v[0]) | ((unsigned)f2bf(v[1]) << 16);
            unsigned q1 = (unsigned)f2bf(v[2]) | ((unsigned)f2bf(v[3]) << 16);
            unsigned q2 = (unsigned)f2bf(v[4]) | ((unsigned)f2bf(v[5]) << 16);
            unsigned q3 = (unsigned)f2bf(v[6]) | ((unsigned)f2bf(v[7]) << 16);
            int slot = srb + 4 + sl; if (slot >= SLOTS) slot -= SLOTS;
            int byte = (ww < 66) ? (g * PXG + slot * 66 + ww) * 16
                                 : (DUMMY + ((int)threadIdx.x & 63) * 16);
            u32x4 q = { q0, q1, q2, q3 };
            *(u32x4*)(smem + byte) = q;
        }
    }

    // ---- compute: output rows rowbase+(wv&1), w-half (wv>>1) ----
    f32x4 acc[2][2];
    {
        f32x4 z = {0.f, 0.f, 0.f, 0.f};
        acc[0][0] = z; acc[0][1] = z; acc[1][0] = z; acc[1][1] = z;
    }
    int rs[3];
    #pragma unroll
    for (int dh = 0; dh < 3; ++dh) {
        int s = srb + (wv & 1) + dh; if (s >= SLOTS) s -= SLOTS;
        rs[dh] = s * 66;
    }
    const int wcb = (wv >> 1) * 32;
    const char* xg = smem + g4 * (PXG * 16);
    #pragma unroll
    for (int dh = 0; dh < 3; ++dh) {
        #pragma unroll
        for (int dw = 0; dw < 3; ++dw) {
            const int tap = dh * 3 + dw;
            #pragma unroll
            for (int m = 0; m < 2; ++m) {
                bf16x8 a = *(const bf16x8*)(xg + (rs[dh] + wcb + m * 16 + col16 + dw) * 16);
                acc[m][0] = __builtin_amdgcn_mfma_f32_16x16x32_bf16(a, wf[tap][0], acc[m][0], 0, 0, 0);
                acc[m][1] = __builtin_amdgcn_mfma_f32_16x16x32_bf16(a, wf[tap][1], acc[m][1], 0, 0, 0);
            }
        }
    }
    {
        float* orow = ob + (size_t)(rowbase + (wv & 1)) * 512 + w0 + wcb;
        #pragma unroll
        for (int m = 0; m < 2; ++m)
            #pragma unroll
            for (int n = 0; n < 2; ++n)
                *(f32x4*)(orow + (size_t)(n * 16 + col16) * HW + m * 16 + g4 * 4) = acc[m][n];
    }

    if (BAR) {
        // drain this iter's gll (per-wave; 4 newest = this iter's stores stay in flight)
        asm volatile("s_waitcnt vmcnt(4)" ::: "memory");
        SCHED();
        asm volatile("s_waitcnt lgkmcnt(0)" ::: "memory");
        SCHED();
        __builtin_amdgcn_s_barrier();
        SCHED();
    }
}

__global__ __launch_bounds__(256, 2)
void conv3x3_mfma(const float* __restrict__ x,
                  const float* __restrict__ wk,
                  float* __restrict__ out) {
    __shared__ __align__(16) char smem[DUMMY + 1024];   // 65280 B -> 2 blocks/CU

    const int tid   = (int)threadIdx.x;
    const int lane  = tid & 63;
    const int wv    = tid >> 6;
    const int wvu   = __builtin_amdgcn_readfirstlane(wv);
    const int col16 = lane & 15;
    const int g4    = lane >> 4;

    const int w0    = blockIdx.x * TW;
    const int hbase = blockIdx.y * 64;
    const int b     = blockIdx.z;

    const float* xb = x + (size_t)b * 32 * HW;
    float* ob = out + (size_t)b * 32 * HW;

    // ---- prologue 1: weights f32 -> stage region scratch ----
    {
        float* ws = (float*)(smem + TILE_B);   // 36992 B <= 2*19456
        for (int i = tid; i < 9216; i += 256) {
            int oc = i / 288;
            ws[oc * 289 + (i - oc * 288)] = wk[i];
        }
    }
    // ---- prologue 2: x rows hbase-1..hbase+2 -> regs (1056 units) ----
    float svp[5][8];
    #pragma unroll
    for (int k = 0; k < 5; ++k) {
        if (k == 4 && tid >= 32) continue;
        int u = (k < 4) ? tid + k * 256 : 1024 + tid;
        int g = u / 264, p = u - g * 264, hh = p / 66, ww = p - hh * 66;
        int row = hbase + hh - 1, cl = w0 + ww - 1;
        bool ok = ((unsigned)row < 512u) & ((unsigned)cl < 512u);
        int rowc = row < 0 ? 0 : (row > 511 ? 511 : row);
        int clc  = cl  < 0 ? 0 : (cl  > 511 ? 511 : cl);
        const float* src = xb + (size_t)(g * 8) * HW + rowc * 512 + clc;
        #pragma unroll
        for (int j = 0; j < 8; ++j) { float v = src[(size_t)j * HW]; svp[k][j] = ok ? v : 0.f; }
    }
    __syncthreads();   // weights scratch visible

    // ---- prologue 3: gather weight fragments to registers ----
    bf16x8 wf[9][2];
    {
        const float* ws = (const float*)(smem + TILE_B);
        #pragma unroll
        for (int tap = 0; tap < 9; ++tap) {
            #pragma unroll
            for (int n = 0; n < 2; ++n) {
                bf16x8 f;
                #pragma unroll
                for (int j = 0; j < 8; ++j)
                    f[j] = (short)f2bf(ws[(n * 16 + col16) * 289 + (g4 * 8 + j) * 9 + tap]);
                wf[tap][n] = f;
            }
        }
    }
    __syncthreads();   // scratch free before gll writes stage

    // ---- prologue 4: write tile slots 0..3; issue stage half 0 (rows 3,4) ----
    #pragma unroll
    for (int k = 0; k < 5; ++k) {
        if (k == 4 && tid >= 32) continue;
        int u = (k < 4) ? tid + k * 256 : 1024 + tid;
        int g = u / 264, p = u - g * 264;       // p = slot*66+ww directly
        unsigned q0 = (unsigned)f2bf(svp[k][0]) | ((unsigned)f2bf(svp[k][1]) << 16);
        unsigned q1 = (unsigned)f2bf(svp[k][2]) | ((unsigned)f2bf(svp[k][3]) << 16);
        unsigned q2 = (unsigned)f2bf(svp[k][4]) | ((unsigned)f2bf(svp[k][5]) << 16);
        unsigned q3 = (unsigned)f2bf(svp[k][6]) | ((unsigned)f2bf(svp[k][7]) << 16);
        u32x4 q = { q0, q1, q2, q3 };
        *(u32x4*)(smem + (g * PXG + p) * 16) = q;
    }
    issue_stage(xb, hbase + 3, w0, smem, 0, wvu);
    __syncthreads();   // full drain: tile 0..3 + stage half 0 ready

    int srb = 0;
    #pragma unroll 1
    for (int t = 0; t < 30; ++t) {
        body<1, 1, 1>(smem, xb, ob, wf, srb, t & 1, hbase + 2 * t, w0, wv, wvu, col16, g4);
        srb += 2; if (srb >= SLOTS) srb -= SLOTS;
    }
    // t = 30: transpose stage[0] (rows 63,64); no new loads
    body<1, 0, 1>(smem, xb, ob, wf, srb, 0, hbase + 60, w0, wv, wvu, col16, g4);
    srb += 2; if (srb >= SLOTS) srb -= SLOTS;
    // t = 31: compute only
    body<0, 0, 0>(smem, xb, ob, wf, srb, 1, hbase + 62, w0, wv, wvu, col16, g4);
}

extern "C" void kernel_launch(void* const* d_in, const int* in_sizes, int n_in,
                              void* d_out, int out_size, void* d_ws, size_t ws_size,
                              hipStream_t stream) {
    const float* x  = (const float*)d_in[0];
    const float* wk = (const float*)d_in[1];
    float* out = (float*)d_out;
    dim3 grid(512 / TW, 512 / 64, 16);   // (8, 8, 16) = 1024 blocks, 2/CU resident
    conv3x3_mfma<<<grid, 256, 0, stream>>>(x, wk, out);
}

// Round 12
// 249.030 us; speedup vs baseline: 1.2496x; 1.0891x over previous
//
#include <hip/hip_runtime.h>
#include <hip/hip_bf16.h>

typedef __attribute__((ext_vector_type(8))) short bf16x8;
typedef __attribute__((ext_vector_type(4))) float f32x4;
typedef __attribute__((ext_vector_type(4))) unsigned int u32x4;

#define HW (512 * 512)
#define TW 64
#define SLOTS 6                  // tile row slots: 4 read + 2 write, disjoint
#define PXG (SLOTS * 66)         // 396 pixels per ic-group
#define TILE_B (4 * PXG * 16)    // 25344: bf16 [g][pixel] MFMA tile
#define STAGE_HALF 19456         // f32 stage: 32ch x 2row x 288B = 18432 real + 1KB pad
#define SREAL 18432
#define DUMMY (TILE_B + 2 * STAGE_HALF)   // 64256; +1KB dummy -> 65280 <= 64KB granule

#define SCHED() __builtin_amdgcn_sched_barrier(0)

__device__ __forceinline__ unsigned short f2bf(float f) {
    unsigned u = __builtin_bit_cast(unsigned, f);
    u += 0x7FFFu + ((u >> 16) & 1u);   // RNE
    return (unsigned short)(u >> 16);
}

__device__ __forceinline__ void gll16(const float* g, char* l) {
    __builtin_amdgcn_global_load_lds(
        (const __attribute__((address_space(1))) void*)g,
        (__attribute__((address_space(3))) void*)l, 16, 0, 0);
}

// stage rows {row0,row0+1} of all 32 ch into stage half: layout [ch:32][hh:2][72 f32].
// 19 x 1KB gll instrs: waves 0-2 issue 5, wave 3 issues 4 (vmcnt(4) drains all).
__device__ __forceinline__ void issue_stage(const float* __restrict__ xb, int row0,
                                            int w0, char* smem, int half, int wvu) {
    const int lane = (int)threadIdx.x & 63;
    char* base = smem + TILE_B + half * STAGE_HALF;
    #pragma unroll
    for (int i = 0; i < 5; ++i) {
        if (wvu == 3 && i == 4) continue;          // wave-uniform
        int ob = (wvu * 5 + i) * 1024;
        int o  = ob + lane * 16;
        int o2 = o < (SREAL - 1) ? o : (SREAL - 1);   // pad lanes -> harmless clamp
        int ch = o2 / 576;
        int rem = o2 - ch * 576;
        int hh = rem / 288;
        int wl = (rem - hh * 288) >> 2;               // 0..71 (mult of 4 for real lanes)
        int row = row0 + hh; row = row < 511 ? row : 511;
        int cb = w0 - 4 + wl;
        cb = cb < 0 ? 0 : (cb > 508 ? 508 : cb);      // stays 16B-aligned
        gll16(xb + (size_t)ch * HW + row * 512 + cb, base + ob);
    }
}

template<bool TRANS, bool GLL, bool BAR>
__device__ __forceinline__ void body(char* smem, const float* __restrict__ xb,
                                     float* __restrict__ ob, bf16x8 (&wf)[9][2],
                                     int srb, int half, int rowbase, int w0,
                                     int wv, int wvu, int col16, int g4) {
    // ---- issue loads for t+1 (other stage half; lands during this body) ----
    if (GLL) issue_stage(xb, rowbase + 5, w0, smem, half ^ 1, wvu);

    // ---- transpose+convert stage[half] (x rows rowbase+3,+4) -> tile slots srb+4,srb+5 ----
    if (TRANS) {
        const char* sb = smem + TILE_B + half * STAGE_HALF;
        const int rowA = rowbase + 3;
        #pragma unroll
        for (int k = 0; k < 3; ++k) {
            if (k == 2 && threadIdx.x >= 32) continue;
            int u = (k < 2) ? (int)threadIdx.x + k * 256 : 512 + (int)threadIdx.x;
            int g = u / 136, r = u - g * 136, sl = r / 68, ww = r - sl * 68;
            float v[8];
            int ba = g * 8 * 576 + sl * 288 + (ww + 3) * 4;
            #pragma unroll
            for (int j = 0; j < 8; ++j) v[j] = *(const float*)(sb + ba + j * 576);
            bool ok = (ww < 66) & ((unsigned)(w0 + ww - 1) < 512u) & (rowA + sl < 512);
            #pragma unroll
            for (int j = 0; j < 8; ++j) v[j] = ok ? v[j] : 0.f;
            unsigned q0 = (unsigned)f2bf(v[0]) | ((unsigned)f2bf(v[1]) << 16);
            unsigned q1 = (unsigned)f2bf(v[2]) | ((unsigned)f2bf(v[3]) << 16);
            unsigned q2 = (unsigned)f2bf(v[4]) | ((unsigned)f2bf(v[5]) << 16);
            unsigned q3 = (unsigned)f2bf(v[6]) | ((unsigned)f2bf(v[7]) << 16);
            int slot = srb + 4 + sl; if (slot >= SLOTS) slot -= SLOTS;
            int byte = (ww < 66) ? (g * PXG + slot * 66 + ww) * 16
                                 : (DUMMY + ((int)threadIdx.x & 63) * 16);
            u32x4 q = { q0, q1, q2, q3 };
            *(u32x4*)(smem + byte) = q;
        }
    }

    // ---- compute: output rows rowbase+(wv&1), w-half (wv>>1) ----
    f32x4 acc[2][2];
    {
        f32x4 z = {0.f, 0.f, 0.f, 0.f};
        acc[0][0] = z; acc[0][1] = z; acc[1][0] = z; acc[1][1] = z;
    }
    int rs[3];
    #pragma unroll
    for (int dh = 0; dh < 3; ++dh) {
        int s = srb + (wv & 1) + dh; if (s >= SLOTS) s -= SLOTS;
        rs[dh] = s * 66;
    }
    const int wcb = (wv >> 1) * 32;
    const char* xg = smem + g4 * (PXG * 16);
    #pragma unroll
    for (int dh = 0; dh < 3; ++dh) {
        #pragma unroll
        for (int dw = 0; dw < 3; ++dw) {
            const int tap = dh * 3 + dw;
            #pragma unroll
            for (int m = 0; m < 2; ++m) {
                bf16x8 a = *(const bf16x8*)(xg + (rs[dh] + wcb + m * 16 + col16 + dw) * 16);
                acc[m][0] = __builtin_amdgcn_mfma_f32_16x16x32_bf16(a, wf[tap][0], acc[m][0], 0, 0, 0);
                acc[m][1] = __builtin_amdgcn_mfma_f32_16x16x32_bf16(a, wf[tap][1], acc[m][1], 0, 0, 0);
            }
        }
    }
    {
        float* orow = ob + (size_t)(rowbase + (wv & 1)) * 512 + w0 + wcb;
        #pragma unroll
        for (int m = 0; m < 2; ++m)
            #pragma unroll
            for (int n = 0; n < 2; ++n)
                *(f32x4*)(orow + (size_t)(n * 16 + col16) * HW + m * 16 + g4 * 4) = acc[m][n];
    }

    if (BAR) {
        // drain this iter's gll (per-wave; 4 newest = this iter's stores stay in flight)
        asm volatile("s_waitcnt vmcnt(4)" ::: "memory");
        SCHED();
        asm volatile("s_waitcnt lgkmcnt(0)" ::: "memory");
        SCHED();
        __builtin_amdgcn_s_barrier();
        SCHED();
    }
}

__global__ __launch_bounds__(256, 2)
void conv3x3_mfma(const float* __restrict__ x,
                  const float* __restrict__ wk,
                  float* __restrict__ out) {
    __shared__ __align__(16) char smem[DUMMY + 1024];   // 65280 B -> 2 blocks/CU

    const int tid   = (int)threadIdx.x;
    const int lane  = tid & 63;
    const int wv    = tid >> 6;
    const int wvu   = __builtin_amdgcn_readfirstlane(wv);
    const int col16 = lane & 15;
    const int g4    = lane >> 4;

    // ---- XCD-coherent remap: the 8 w-neighbor blocks (same rows) share an XCD.
    // Default assignment: XCD = wgid % 8. Bijective permutation of (8,8,16):
    //   xcd = yq  (h-strip); within an XCD, consecutive dispatches sweep xq = 0..7,
    //   so co-resident blocks' 288B read strips tile complete 2KB rows.
    const int wg  = (int)blockIdx.x;
    const int xcd = wg & 7;          // = yq
    const int i   = wg >> 3;
    const int xq  = i & 7;           // w-tile
    const int pg  = xcd + 8 * (i >> 3);
    const int yq  = pg & 7;          // h-strip
    const int zq  = pg >> 3;         // batch

    const int w0    = xq * TW;
    const int hbase = yq * 64;
    const int b     = zq;

    const float* xb = x + (size_t)b * 32 * HW;
    float* ob = out + (size_t)b * 32 * HW;

    // ---- prologue 1: weights f32 -> stage region scratch ----
    {
        float* ws = (float*)(smem + TILE_B);   // 36992 B <= 2*19456
        for (int i2 = tid; i2 < 9216; i2 += 256) {
            int oc = i2 / 288;
            ws[oc * 289 + (i2 - oc * 288)] = wk[i2];
        }
    }
    // ---- prologue 2: x rows hbase-1..hbase+2 -> regs (1056 units) ----
    float svp[5][8];
    #pragma unroll
    for (int k = 0; k < 5; ++k) {
        if (k == 4 && tid >= 32) continue;
        int u = (k < 4) ? tid + k * 256 : 1024 + tid;
        int g = u / 264, p = u - g * 264, hh = p / 66, ww = p - hh * 66;
        int row = hbase + hh - 1, cl = w0 + ww - 1;
        bool ok = ((unsigned)row < 512u) & ((unsigned)cl < 512u);
        int rowc = row < 0 ? 0 : (row > 511 ? 511 : row);
        int clc  = cl  < 0 ? 0 : (cl  > 511 ? 511 : cl);
        const float* src = xb + (size_t)(g * 8) * HW + rowc * 512 + clc;
        #pragma unroll
        for (int j = 0; j < 8; ++j) { float v = src[(size_t)j * HW]; svp[k][j] = ok ? v : 0.f; }
    }
    __syncthreads();   // weights scratch visible

    // ---- prologue 3: gather weight fragments to registers ----
    bf16x8 wf[9][2];
    {
        const float* ws = (const float*)(smem + TILE_B);
        #pragma unroll
        for (int tap = 0; tap < 9; ++tap) {
            #pragma unroll
            for (int n = 0; n < 2; ++n) {
                bf16x8 f;
                #pragma unroll
                for (int j = 0; j < 8; ++j)
                    f[j] = (short)f2bf(ws[(n * 16 + col16) * 289 + (g4 * 8 + j) * 9 + tap]);
                wf[tap][n] = f;
            }
        }
    }
    __syncthreads();   // scratch free before gll writes stage

    // ---- prologue 4: write tile slots 0..3; issue stage half 0 (rows 3,4) ----
    #pragma unroll
    for (int k = 0; k < 5; ++k) {
        if (k == 4 && tid >= 32) continue;
        int u = (k < 4) ? tid + k * 256 : 1024 + tid;
        int g = u / 264, p = u - g * 264;       // p = slot*66+ww directly
        unsigned q0 = (unsigned)f2bf(svp[k][0]) | ((unsigned)f2bf(svp[k][1]) << 16);
        unsigned q1 = (unsigned)f2bf(svp[k][2]) | ((unsigned)f2bf(svp[k][3]) << 16);
        unsigned q2 = (unsigned)f2bf(svp[k][4]) | ((unsigned)f2bf(svp[k][5]) << 16);
        unsigned q3 = (unsigned)f2bf(svp[k][6]) | ((unsigned)f2bf(svp[k][7]) << 16);
        u32x4 q = { q0, q1, q2, q3 };
        *(u32x4*)(smem + (g * PXG + p) * 16) = q;
    }
    issue_stage(xb, hbase + 3, w0, smem, 0, wvu);
    __syncthreads();   // full drain: tile 0..3 + stage half 0 ready

    int srb = 0;
    #pragma unroll 1
    for (int t = 0; t < 30; ++t) {
        body<1, 1, 1>(smem, xb, ob, wf, srb, t & 1, hbase + 2 * t, w0, wv, wvu, col16, g4);
        srb += 2; if (srb >= SLOTS) srb -= SLOTS;
    }
    // t = 30: transpose stage[0] (rows 63,64); no new loads
    body<1, 0, 1>(smem, xb, ob, wf, srb, 0, hbase + 60, w0, wv, wvu, col16, g4);
    srb += 2; if (srb >= SLOTS) srb -= SLOTS;
    // t = 31: compute only
    body<0, 0, 0>(smem, xb, ob, wf, srb, 1, hbase + 62, w0, wv, wvu, col16, g4);
}

extern "C" void kernel_launch(void* const* d_in, const int* in_sizes, int n_in,
                              void* d_out, int out_size, void* d_ws, size_t ws_size,
                              hipStream_t stream) {
    const float* x  = (const float*)d_in[0];
    const float* wk = (const float*)d_in[1];
    float* out = (float*)d_out;
    conv3x3_mfma<<<dim3(1024, 1, 1), 256, 0, stream>>>(x, wk, out);
}